// Round 1
// baseline (9772.623 us; speedup 1.0000x reference)
//
#include <hip/hip_runtime.h>
#include <math.h>

#define BH   64
#define SEQ  1024
#define DIM  64
#define QT   2            // q rows per block
#define KB   32           // k tile
#define NTH  256
#define ROWS (QT*BH)      // 128 flash rows per block
#define NEGV (-1000000.0f)

// Block layout:
//   thread t -> row r = t & 127  (r = ql*64 + b), k-half kh = t >> 7
//   wave 0: rows 0..63  (ql=0) kh=0 | wave 1: rows 64..127 (ql=1) kh=0
//   wave 2: rows 0..63  (ql=0) kh=1 | wave 3: rows 64..127 (ql=1) kh=1
//   => pos-tile LDS reads are wave-uniform (broadcast, conflict-free).
__global__ __launch_bounds__(NTH, 3)
void rpr_attn(const float* __restrict__ Qg, const float* __restrict__ Kg,
              const float* __restrict__ Vg, const float* __restrict__ PKg,
              const float* __restrict__ PVg, const int* __restrict__ VLg,
              float* __restrict__ Og)
{
    __shared__ float pk_s[QT][KB][DIM];     // 16 KB  pos_k tile (per q of pair)
    __shared__ float pv_s[QT][KB][DIM];     // 16 KB  pos_v tile
    __shared__ float p_s[ROWS][KB + 1];     // 16.9 KB scores/probs (padded)
    __shared__ float red_max[ROWS][2];
    __shared__ float red_sum[ROWS][2];

    const int t  = threadIdx.x;
    const int r  = t & (ROWS - 1);
    const int kh = t >> 7;            // 0/1: which half of the k-tile
    const int ql = r >> 6;            // 0/1: which q of the pair
    const int b  = r & (BH - 1);
    const int q0 = blockIdx.x * QT;
    const int q  = q0 + ql;

    const int vlen = VLg[b];

    // Q row in registers (16 float4)
    float4 qreg[DIM / 4];
    {
        const float4* qp = reinterpret_cast<const float4*>(Qg + ((size_t)b * SEQ + q) * DIM);
        #pragma unroll
        for (int i = 0; i < DIM / 4; i++) qreg[i] = qp[i];
    }

    float m = -INFINITY, l = 0.0f;
    float acc[32];                    // output d in [kh*32, kh*32+32)
    #pragma unroll
    for (int i = 0; i < 32; i++) acc[i] = 0.0f;

    for (int kt = 0; kt < SEQ; kt += KB) {
        __syncthreads();  // A: previous tile's p_s / pos-tile reads complete

        // ---- stage pos_k / pos_v tiles (contiguous 8 KB per q slice, coalesced) ----
        {
            const int total4 = QT * KB * DIM / 4;   // 2048 float4
            #pragma unroll
            for (int c = 0; c < total4; c += NTH) {
                const int i4  = c + t;
                const int fq  = i4 >> 9;            // / (KB*DIM/4 = 512)
                const int rem = i4 & 511;
                const float4* spk = reinterpret_cast<const float4*>(
                    PKg + ((size_t)(q0 + fq) * SEQ + kt) * DIM) + rem;
                const float4* spv = reinterpret_cast<const float4*>(
                    PVg + ((size_t)(q0 + fq) * SEQ + kt) * DIM) + rem;
                reinterpret_cast<float4*>(&pk_s[fq][0][0])[rem] = *spk;
                reinterpret_cast<float4*>(&pv_s[fq][0][0])[rem] = *spv;
            }
        }
        __syncthreads();  // B: tiles staged

        // ---- scores: s[r][k] = Q . (K + pos_k), this thread does 16 k's ----
        float tmax = -INFINITY;
        #pragma unroll
        for (int kk = 0; kk < KB / 2; kk++) {
            const int kl = kh * (KB / 2) + kk;
            const int kg = kt + kl;
            const float4* kp = reinterpret_cast<const float4*>(Kg + ((size_t)b * SEQ + kg) * DIM);
            const float4* pp = reinterpret_cast<const float4*>(&pk_s[ql][kl][0]);
            float sx = 0.f, sy = 0.f, sz = 0.f, sw = 0.f;
            #pragma unroll
            for (int i = 0; i < DIM / 4; i++) {
                const float4 kv = kp[i];
                const float4 pv = pp[i];   // wave-uniform LDS broadcast
                sx += qreg[i].x * (kv.x + pv.x);
                sy += qreg[i].y * (kv.y + pv.y);
                sz += qreg[i].z * (kv.z + pv.z);
                sw += qreg[i].w * (kv.w + pv.w);
            }
            float s = (sx + sy) + (sz + sw);
            s = (kg < vlen) ? s * 0.125f : NEGV;   // scale = 1/sqrt(64); mask AFTER scale like ref
            p_s[r][kl] = s;                        // raw score
            tmax = fmaxf(tmax, s);
        }
        red_max[r][kh] = tmax;
        __syncthreads();  // C: both halves' maxima visible

        const float mnew  = fmaxf(m, fmaxf(red_max[r][0], red_max[r][1]));
        const float alpha = __expf(m - mnew);      // first tile: exp(-inf)=0
        m = mnew;

        float psum = 0.0f;
        #pragma unroll
        for (int kk = 0; kk < KB / 2; kk++) {
            const int kl = kh * (KB / 2) + kk;
            const float p = __expf(p_s[r][kl] - mnew);  // masked: exp(-1e6-m) == 0
            p_s[r][kl] = p;
            psum += p;
        }
        red_sum[r][kh] = psum;

        #pragma unroll
        for (int i = 0; i < 32; i++) acc[i] *= alpha;
        __syncthreads();  // D: probs + sums visible

        l = l * alpha + red_sum[r][0] + red_sum[r][1];

        // ---- PV: acc[d] += p[k] * (V[b,k,d] + pos_v[q,k,d]) for d in this half ----
        const int d0 = kh * 32;
        #pragma unroll 4
        for (int kk = 0; kk < KB; kk++) {
            const float p = p_s[r][kk];
            const float4* vp  = reinterpret_cast<const float4*>(
                Vg + ((size_t)b * SEQ + kt + kk) * DIM + d0);
            const float4* pvp = reinterpret_cast<const float4*>(&pv_s[ql][kk][d0]);
            #pragma unroll
            for (int i = 0; i < 8; i++) {
                const float4 vv = vp[i];
                const float4 w  = pvp[i];  // wave-uniform LDS broadcast
                acc[4*i+0] += p * (vv.x + w.x);
                acc[4*i+1] += p * (vv.y + w.y);
                acc[4*i+2] += p * (vv.z + w.z);
                acc[4*i+3] += p * (vv.w + w.w);
            }
        }
    }

    // ---- epilogue: out = acc / l ----
    const float invl = 1.0f / l;
    float4* op = reinterpret_cast<float4*>(Og + ((size_t)b * SEQ + q) * DIM + kh * 32);
    #pragma unroll
    for (int i = 0; i < 8; i++) {
        float4 o;
        o.x = acc[4*i+0] * invl;
        o.y = acc[4*i+1] * invl;
        o.z = acc[4*i+2] * invl;
        o.w = acc[4*i+3] * invl;
        op[i] = o;
    }
}

extern "C" void kernel_launch(void* const* d_in, const int* in_sizes, int n_in,
                              void* d_out, int out_size, void* d_ws, size_t ws_size,
                              hipStream_t stream) {
    const float* Qg  = (const float*)d_in[0];
    const float* Kg  = (const float*)d_in[1];
    const float* Vg  = (const float*)d_in[2];
    const float* PKg = (const float*)d_in[3];
    const float* PVg = (const float*)d_in[4];
    const int*   VLg = (const int*)d_in[5];
    float* Og = (float*)d_out;

    dim3 grid(SEQ / QT);   // 512 blocks: one per q-pair, covering all 64 batch-heads
    dim3 block(NTH);
    hipLaunchKernelGGL(rpr_attn, grid, block, 0, stream,
                       Qg, Kg, Vg, PKg, PVg, VLg, Og);
}

// Round 3
// 2782.894 us; speedup vs baseline: 3.5117x; 3.5117x over previous
//
#include <hip/hip_runtime.h>
#include <math.h>

#define SEQ  1024
#define DIM  64
#define QT   2            // q rows per block (and per thread)
#define KB   32           // k tile
#define CK   8            // k chunk (scores+probs in regs)
#define NTH  256
#define NEGV (-1000000.0f)

// quad shuffles on the VALU pipe (DPP), lanes grouped as b*4+dq
__device__ __forceinline__ float qxor1(float x) {
    return __int_as_float(__builtin_amdgcn_mov_dpp(__float_as_int(x), 0xB1, 0xF, 0xF, true)); // quad_perm(1,0,3,2)
}
__device__ __forceinline__ float qxor2(float x) {
    return __int_as_float(__builtin_amdgcn_mov_dpp(__float_as_int(x), 0x4E, 0xF, 0xF, true)); // quad_perm(2,3,0,1)
}

#define DOT4(S, QV, KV, PV)                         \
    S += QV.x * (KV.x + PV.x);                      \
    S += QV.y * (KV.y + PV.y);                      \
    S += QV.z * (KV.z + PV.z);                      \
    S += QV.w * (KV.w + PV.w);

#define PVACC(A, PJ, VV, WV)                        \
    A.x += PJ * (VV.x + WV.x);                      \
    A.y += PJ * (VV.y + WV.y);                      \
    A.z += PJ * (VV.z + WV.z);                      \
    A.w += PJ * (VV.w + WV.w);

__global__ __launch_bounds__(NTH, 3)
void rpr_attn2(const float* __restrict__ Qg, const float* __restrict__ Kg,
               const float* __restrict__ Vg, const float* __restrict__ PKg,
               const float* __restrict__ PVg, const int* __restrict__ VLg,
               float* __restrict__ Og)
{
    __shared__ float pk_s[QT][KB][DIM];   // 16 KB
    __shared__ float pv_s[QT][KB][DIM];   // 16 KB

    const int t  = threadIdx.x;
    const int dq = t & 3;          // d-quarter: 16 floats starting at dq*16
    const int b  = t >> 2;         // batch-head 0..63
    const int q0 = blockIdx.x * QT;
    const int vlen = VLg[b];

    const size_t brow  = (size_t)b * (SEQ * DIM);
    const float* kbase = Kg + brow + dq * 16;
    const float* vbase = Vg + brow + dq * 16;

    // Q fragments: 2 q's x 16 d
    float4 qreg[QT][4];
    #pragma unroll
    for (int ql = 0; ql < QT; ql++) {
        const float4* qp = reinterpret_cast<const float4*>(Qg + brow + (size_t)(q0 + ql) * DIM + dq * 16);
        #pragma unroll
        for (int i = 0; i < 4; i++) qreg[ql][i] = qp[i];
    }

    float  m[QT], l[QT];
    float4 acc[QT][4];
    #pragma unroll
    for (int ql = 0; ql < QT; ql++) {
        m[ql] = -INFINITY;  l[ql] = 0.0f;
        #pragma unroll
        for (int i = 0; i < 4; i++) acc[ql][i] = make_float4(0.f, 0.f, 0.f, 0.f);
    }

    for (int kt = 0; kt < SEQ; kt += KB) {
        __syncthreads();   // previous tile's LDS reads complete

        // ---- stage pos tiles: 2 x 16 KB, fully coalesced float4, linear LDS ----
        #pragma unroll
        for (int c = 0; c < 4; c++) {
            const int e   = c * NTH + t;      // float4 index 0..1023
            const int fq  = e >> 9;           // q slice (512 float4 each)
            const int rem = e & 511;
            const size_t goff = ((size_t)(q0 + fq) * SEQ + kt) * DIM + (size_t)rem * 4;
            reinterpret_cast<float4*>(&pk_s[0][0][0])[e] = *reinterpret_cast<const float4*>(PKg + goff);
            reinterpret_cast<float4*>(&pv_s[0][0][0])[e] = *reinterpret_cast<const float4*>(PVg + goff);
        }
        __syncthreads();   // tiles visible

        if (kt < vlen) {   // per-thread skip of fully-masked tiles (barriers stay uniform)
            #pragma unroll
            for (int c = 0; c < KB / CK; c++) {
                float s[QT][CK];

                // ---- partial dots: K loaded once, both q's consume in-reg ----
                #pragma unroll
                for (int j = 0; j < CK; j++) {
                    const int kk = c * CK + j;
                    const int kg = kt + kk;
                    const float4* kp = reinterpret_cast<const float4*>(kbase + (size_t)kg * DIM);
                    const float4 k0 = kp[0], k1 = kp[1], k2 = kp[2], k3 = kp[3];
                    #pragma unroll
                    for (int ql = 0; ql < QT; ql++) {
                        const float4* pp = reinterpret_cast<const float4*>(&pk_s[ql][kk][dq * 16]);
                        const float4 p0 = pp[0], p1 = pp[1], p2 = pp[2], p3 = pp[3];
                        float sv = 0.0f;
                        DOT4(sv, qreg[ql][0], k0, p0);
                        DOT4(sv, qreg[ql][1], k1, p1);
                        DOT4(sv, qreg[ql][2], k2, p2);
                        DOT4(sv, qreg[ql][3], k3, p3);
                        s[ql][j] = sv;
                    }
                }

                // ---- close dots across the 4 d-quarter lanes, scale, mask ----
                #pragma unroll
                for (int ql = 0; ql < QT; ql++) {
                    #pragma unroll
                    for (int j = 0; j < CK; j++) {
                        float v = s[ql][j];
                        v += qxor1(v);
                        v += qxor2(v);
                        const int kg = kt + c * CK + j;
                        s[ql][j] = (kg < vlen) ? v * 0.125f : NEGV;
                    }
                }

                // ---- online softmax (thread-local; p overwrites s) ----
                #pragma unroll
                for (int ql = 0; ql < QT; ql++) {
                    float tmax = s[ql][0];
                    #pragma unroll
                    for (int j = 1; j < CK; j++) tmax = fmaxf(tmax, s[ql][j]);
                    const float mnew  = fmaxf(m[ql], tmax);
                    const float alpha = __expf(m[ql] - mnew);   // first tile: exp(-inf)=0
                    float psum = 0.0f;
                    #pragma unroll
                    for (int j = 0; j < CK; j++) {
                        const float p = __expf(s[ql][j] - mnew); // masked: exp(-1e6-m)=0
                        s[ql][j] = p;
                        psum += p;
                    }
                    l[ql] = l[ql] * alpha + psum;
                    m[ql] = mnew;
                    #pragma unroll
                    for (int i = 0; i < 4; i++) {
                        acc[ql][i].x *= alpha; acc[ql][i].y *= alpha;
                        acc[ql][i].z *= alpha; acc[ql][i].w *= alpha;
                    }
                }

                // ---- PV: V loaded once, both q's consume in-reg ----
                #pragma unroll
                for (int j = 0; j < CK; j++) {
                    const int kk = c * CK + j;
                    const int kg = kt + kk;
                    const float4* vp = reinterpret_cast<const float4*>(vbase + (size_t)kg * DIM);
                    const float4 v0 = vp[0], v1 = vp[1], v2 = vp[2], v3 = vp[3];
                    #pragma unroll
                    for (int ql = 0; ql < QT; ql++) {
                        const float4* wp = reinterpret_cast<const float4*>(&pv_s[ql][kk][dq * 16]);
                        const float4 w0 = wp[0], w1 = wp[1], w2 = wp[2], w3 = wp[3];
                        const float pj = s[ql][j];
                        PVACC(acc[ql][0], pj, v0, w0);
                        PVACC(acc[ql][1], pj, v1, w1);
                        PVACC(acc[ql][2], pj, v2, w2);
                        PVACC(acc[ql][3], pj, v3, w3);
                    }
                }
            }
        }
    }

    // ---- epilogue ----
    #pragma unroll
    for (int ql = 0; ql < QT; ql++) {
        const float inv = 1.0f / l[ql];
        float4* op = reinterpret_cast<float4*>(Og + brow + (size_t)(q0 + ql) * DIM + dq * 16);
        #pragma unroll
        for (int i = 0; i < 4; i++) {
            float4 o;
            o.x = acc[ql][i].x * inv;  o.y = acc[ql][i].y * inv;
            o.z = acc[ql][i].z * inv;  o.w = acc[ql][i].w * inv;
            op[i] = o;
        }
    }
}

extern "C" void kernel_launch(void* const* d_in, const int* in_sizes, int n_in,
                              void* d_out, int out_size, void* d_ws, size_t ws_size,
                              hipStream_t stream) {
    const float* Qg  = (const float*)d_in[0];
    const float* Kg  = (const float*)d_in[1];
    const float* Vg  = (const float*)d_in[2];
    const float* PKg = (const float*)d_in[3];
    const float* PVg = (const float*)d_in[4];
    const int*   VLg = (const int*)d_in[5];
    float* Og = (float*)d_out;

    dim3 grid(SEQ / QT);   // 512 blocks: q-pair x all 64 batch-heads
    dim3 block(NTH);
    hipLaunchKernelGGL(rpr_attn2, grid, block, 0, stream,
                       Qg, Kg, Vg, PKg, PVg, VLg, Og);
}